// Round 1
// baseline (247.707 us; speedup 1.0000x reference)
//
#include <hip/hip_runtime.h>

#define N_NODES 1024
#define C_CH    128
#define L_ELL   16
#define N_ELEM  10
#define K3      11
#define K2      4

__device__ __forceinline__ int swz3(int w) { return w ^ (((w >> 8) & 7) << 2); }

__global__ __launch_bounds__(256) void sym_contract_kernel(
    const float* __restrict__ node_feats,   // [N, C, 16]
    const float* __restrict__ node_attrs,   // [N, 10]
    const float* __restrict__ U03, const float* __restrict__ W03,
    const float* __restrict__ U02, const float* __restrict__ W02,
    const float* __restrict__ U01, const float* __restrict__ W01,
    const float* __restrict__ U13, const float* __restrict__ W13,
    const float* __restrict__ U12, const float* __restrict__ W12,
    const float* __restrict__ U11, const float* __restrict__ W11,
    float* __restrict__ feats_out)          // [N, C*4]  (= d_out, pre-linear)
{
  __shared__ float T3[4 * 4096];        // [m][i1][i2][i3], XOR-swizzled
  __shared__ float T2[4 * 16 * 17];     // [m][i1][i2], row-padded to 17
  __shared__ float T1[4 * 16];          // [m][i1]
  __shared__ unsigned short nodelist[N_NODES];
  __shared__ float wrow[32];
  __shared__ int cnt;

  const int e   = blockIdx.x / C_CH;
  const int c   = blockIdx.x % C_CH;
  const int tid = threadIdx.x;

  if (tid == 0) cnt = 0;
  if (tid < 32) {
    float v;
    if (tid < 11)       v = W03[(e * K3 + tid) * C_CH + c];
    else if (tid < 15)  v = W02[(e * K2 + (tid - 11)) * C_CH + c];
    else if (tid == 15) v = W01[e * C_CH + c];
    else if (tid < 27)  v = W13[(e * K3 + (tid - 16)) * C_CH + c];
    else if (tid < 31)  v = W12[(e * K2 + (tid - 27)) * C_CH + c];
    else                v = W11[e * C_CH + c];
    wrow[tid] = v;
  }
  __syncthreads();

  // --- node list for this element ---
  for (int b = tid; b < N_NODES; b += 256)
    if (node_attrs[b * N_ELEM + e] > 0.5f) {
      int p = atomicAdd(&cnt, 1);
      nodelist[p] = (unsigned short)b;
    }

  // --- T3 = U3 contracted with W3 over k (per m = merged d index) ---
  for (int w = tid; w < 4 * 4096; w += 256) {
    const int m = w >> 12;
    const int r = w & 4095;               // i1*256 + i2*16 + i3
    const float* Up;
    const float* wp;
    if (m == 0) { Up = U03 + r * K3;                    wp = wrow;      }
    else        { Up = U13 + ((m - 1) * 4096 + r) * K3; wp = wrow + 16; }
    float s = 0.f;
    #pragma unroll
    for (int k = 0; k < K3; ++k) s += Up[k] * wp[k];
    T3[swz3(w)] = s;
  }
  // --- T2 ---
  for (int w = tid; w < 4 * 256; w += 256) {
    const int m = w >> 8;
    const int r = w & 255;                // i1*16 + i2
    const float* Up;
    const float* wp;
    if (m == 0) { Up = U02 + r * K2;                   wp = wrow + 11; }
    else        { Up = U12 + ((m - 1) * 256 + r) * K2; wp = wrow + 27; }
    float s = 0.f;
    #pragma unroll
    for (int k = 0; k < K2; ++k) s += Up[k] * wp[k];
    T2[m * 272 + (r >> 4) * 17 + (r & 15)] = s;
  }
  // --- T1 ---
  if (tid < 64) {
    const int m  = tid >> 4;
    const int i1 = tid & 15;
    T1[m * 16 + i1] = (m == 0) ? U01[i1] * wrow[15]
                               : U11[(m - 1) * 16 + i1] * wrow[31];
  }
  __syncthreads();

  // --- per-node contraction: wave = m, lane = (nsub: node-of-4, i1: row) ---
  const int m    = tid >> 6;
  const int lane = tid & 63;
  const int nsub = lane >> 4;
  const int i1   = lane & 15;
  const int xorv = (i1 & 7) << 2;
  const int t3base0 = m * 4096 + i1 * 256;
  const int total = cnt;

  for (int q = 0; q < total; q += 4) {
    const int idx    = q + nsub;
    const bool active = idx < total;
    const int b = nodelist[active ? idx : 0];
    const float* xg = node_feats + (b * C_CH + c) * L_ELL;
    const float4 xa = ((const float4*)xg)[0];
    const float4 xb = ((const float4*)xg)[1];
    const float4 xc = ((const float4*)xg)[2];
    const float4 xd = ((const float4*)xg)[3];
    const float xs[16] = {xa.x, xa.y, xa.z, xa.w, xb.x, xb.y, xb.z, xb.w,
                          xc.x, xc.y, xc.z, xc.w, xd.x, xd.y, xd.z, xd.w};
    float s2 = 0.f;
    #pragma unroll
    for (int i2 = 0; i2 < 16; ++i2) {
      const int base = t3base0 + i2 * 16;
      const float4 t0 = *(const float4*)&T3[(base + 0)  ^ xorv];
      const float4 t1 = *(const float4*)&T3[(base + 4)  ^ xorv];
      const float4 t2 = *(const float4*)&T3[(base + 8)  ^ xorv];
      const float4 t3 = *(const float4*)&T3[(base + 12) ^ xorv];
      const float dot =
          t0.x * xs[0]  + t0.y * xs[1]  + t0.z * xs[2]  + t0.w * xs[3]
        + t1.x * xs[4]  + t1.y * xs[5]  + t1.z * xs[6]  + t1.w * xs[7]
        + t2.x * xs[8]  + t2.y * xs[9]  + t2.z * xs[10] + t2.w * xs[11]
        + t3.x * xs[12] + t3.y * xs[13] + t3.z * xs[14] + t3.w * xs[15];
      s2 += (dot + T2[m * 272 + i1 * 17 + i2]) * xs[i2];
    }
    const float x_i1 = xg[i1];          // dynamic index -> reload (L1 hit)
    float r = (s2 + T1[m * 16 + i1]) * x_i1;
    r += __shfl_xor(r, 1);
    r += __shfl_xor(r, 2);
    r += __shfl_xor(r, 4);
    r += __shfl_xor(r, 8);
    if (active && i1 == 0)
      feats_out[b * 512 + c * 4 + m] = r;
  }
}

__global__ __launch_bounds__(256) void linear_kernel(
    const float* __restrict__ sc,
    const float* __restrict__ lin0,
    const float* __restrict__ lin1,
    float* __restrict__ io)             // d_out, in-place per-row
{
  __shared__ float f[512];              // [c][m]
  const int b   = blockIdx.x;
  const int tid = threadIdx.x;
  const float* row = io + b * 512;
  if (tid < 128) ((float4*)f)[tid] = ((const float4*)row)[tid];
  __syncthreads();
  const float inv_sqrt_c = 0.088388347648318447f;   // 1/sqrt(128)
  #pragma unroll
  for (int rep = 0; rep < 2; ++rep) {
    const int o = tid + rep * 256;
    float acc = 0.f;
    if (o < 128) {
      const int fo = o;
      #pragma unroll 4
      for (int ci = 0; ci < 128; ++ci) acc += f[ci * 4] * lin0[ci * 128 + fo];
    } else {
      const int oo = o - 128;
      const int fo = oo / 3;
      const int dd = oo - fo * 3;
      #pragma unroll 4
      for (int ci = 0; ci < 128; ++ci) acc += f[ci * 4 + 1 + dd] * lin1[ci * 128 + fo];
    }
    io[b * 512 + o] = acc * inv_sqrt_c + sc[b * 512 + o];
  }
}

extern "C" void kernel_launch(void* const* d_in, const int* in_sizes, int n_in,
                              void* d_out, int out_size, void* d_ws, size_t ws_size,
                              hipStream_t stream) {
  const float* node_feats = (const float*)d_in[0];
  const float* sc         = (const float*)d_in[1];
  const float* node_attrs = (const float*)d_in[2];
  const float* U01  = (const float*)d_in[3];
  const float* W01  = (const float*)d_in[4];
  const float* U02  = (const float*)d_in[5];
  const float* W02  = (const float*)d_in[6];
  const float* U03  = (const float*)d_in[7];
  const float* W03  = (const float*)d_in[8];
  const float* lin0 = (const float*)d_in[9];
  const float* U11  = (const float*)d_in[10];
  const float* W11  = (const float*)d_in[11];
  const float* U12  = (const float*)d_in[12];
  const float* W12  = (const float*)d_in[13];
  const float* U13  = (const float*)d_in[14];
  const float* W13  = (const float*)d_in[15];
  const float* lin1 = (const float*)d_in[16];
  float* out = (float*)d_out;

  sym_contract_kernel<<<N_ELEM * C_CH, 256, 0, stream>>>(
      node_feats, node_attrs,
      U03, W03, U02, W02, U01, W01,
      U13, W13, U12, W12, U11, W11, out);
  linear_kernel<<<N_NODES, 256, 0, stream>>>(sc, lin0, lin1, out);
}